// Round 1
// baseline (86.459 us; speedup 1.0000x reference)
//
#include <hip/hip_runtime.h>
#include <math.h>

#define T_DIM 4096
#define F_DIM 256
#define NROWS 4096          // B*C*F = 16*1*256
#define CHUNK 16            // elements per thread; 256 threads * 16 = 4096 = T
#define LOG_EPS_F (-13.815510557964274f)   // ln(1e-6)

__device__ __constant__ float d_slist[4] = {0.015f, 0.02f, 0.04f, 0.08f};

__global__ __launch_bounds__(256, 4)
void pcen_kernel(const float* __restrict__ x,
                 const float* __restrict__ log_alpha,
                 const float* __restrict__ log_delta,
                 const float* __restrict__ log_r,
                 const float* __restrict__ z_ks,
                 float* __restrict__ out)
{
    const int tid  = threadIdx.x;
    const int lane = tid & 63;
    const int wid  = tid >> 6;
    const int rid  = blockIdx.x;
    const int f    = rid & (F_DIM - 1);

    __shared__ float sred[4];
    __shared__ float sE[4];
    __shared__ float sSum;

    // ---- softmax denominator over ALL K*F = 1024 z entries (reference normalizes globally) ----
    float zs = expf(z_ks[tid])       + expf(z_ks[tid + 256])
             + expf(z_ks[tid + 512]) + expf(z_ks[tid + 768]);
    #pragma unroll
    for (int d = 32; d >= 1; d >>= 1) zs += __shfl_down(zs, d, 64);
    if (lane == 0) sred[wid] = zs;
    __syncthreads();
    if (tid == 0) sSum = sred[0] + sred[1] + sred[2] + sred[3];
    __syncthreads();
    const float invsum = 1.0f / sSum;

    float wk[4];
    #pragma unroll
    for (int k = 0; k < 4; ++k) wk[k] = expf(z_ks[k * F_DIM + f]) * invsum;
    const float alpha = expf(log_alpha[f]);
    const float delta = expf(log_delta[f]);
    const float rr    = expf(log_r[f]);
    const float dr    = expf(rr * logf(delta));   // delta^r (delta > 0)

    // ---- load this thread's 16 contiguous elements ----
    const size_t base = (size_t)rid * T_DIM + (size_t)tid * CHUNK;
    float xv[CHUNK];
    {
        const float4* xp = (const float4*)(x + base);
        #pragma unroll
        for (int j = 0; j < 4; ++j) {
            float4 v = xp[j];
            xv[4*j+0] = v.x; xv[4*j+1] = v.y; xv[4*j+2] = v.z; xv[4*j+3] = v.w;
        }
    }

    float Mv[CHUNK];
    #pragma unroll
    for (int i = 0; i < CHUNK; ++i) Mv[i] = 0.0f;

    #pragma unroll 1
    for (int k = 0; k < 4; ++k) {
        const float s = d_slist[k];
        const float a = 1.0f - s;
        const float a2 = a * a, a4 = a2 * a2, a8 = a4 * a4;
        const float A  = a8 * a8;                       // a^16 (per-thread chunk factor)
        const float A2 = A*A, A4 = A2*A2, A8 = A4*A4, A16 = A8*A8, A32 = A16*A16;
        const float A64 = A32 * A32;                    // a^1024 (per-wave chunk factor)

        // A^lane and A^(63-lane) via binary exponentiation (exact-ish, no transcendentals)
        float pAl = 1.0f, pAr = 1.0f;
        {
            float q = A;
            const int rl = 63 - lane;
            #pragma unroll
            for (int b = 0; b < 6; ++b) {
                if ((lane >> b) & 1) pAl *= q;
                if ((rl   >> b) & 1) pAr *= q;
                q *= q;
            }
        }

        // ===== forward: y[n] = a*y[n-1] + s*x[n], y[0] = x[0] =====
        float y[CHUNK];
        y[0] = (tid == 0) ? xv[0] : s * xv[0];
        #pragma unroll
        for (int i = 1; i < CHUNK; ++i) y[i] = fmaf(a, y[i-1], s * xv[i]);

        // wave-level scan of per-thread carries (uniform multiplier A)
        float e = y[CHUNK-1];
        {
            float Ad = A;
            #pragma unroll
            for (int d = 1; d < 64; d <<= 1) {
                float t = __shfl_up(e, d, 64);
                if (lane >= d) e = fmaf(Ad, t, e);
                Ad *= Ad;
            }
        }
        __syncthreads();                 // protect sE reuse from previous iteration
        if (lane == 63) sE[wid] = e;
        __syncthreads();
        float C = 0.0f;
        for (int j = 0; j < wid; ++j) C = fmaf(A64, C, sE[j]);   // carry entering this wave
        float eex = __shfl_up(e, 1, 64);
        const float c = ((lane == 0) ? 0.0f : eex) + pAl * C;    // carry entering this thread
        {
            float pw = a;
            #pragma unroll
            for (int i = 0; i < CHUNK; ++i) { y[i] = fmaf(pw, c, y[i]); pw *= a; }
        }

        // ===== backward (in place): z[n] = a*z[n+1] + s*y[n], z[T-1] = y[T-1] =====
        y[CHUNK-1] = (tid == 255) ? y[CHUNK-1] : s * y[CHUNK-1];
        #pragma unroll
        for (int i = CHUNK-2; i >= 0; --i) y[i] = fmaf(a, y[i+1], s * y[i]);

        float eb = y[0];
        {
            float Ad = A;
            #pragma unroll
            for (int d = 1; d < 64; d <<= 1) {
                float t = __shfl_down(eb, d, 64);
                if (lane < 64 - d) eb = fmaf(Ad, t, eb);
                Ad *= Ad;
            }
        }
        __syncthreads();
        if (lane == 0) sE[wid] = eb;
        __syncthreads();
        float Cb = 0.0f;
        for (int j = 3; j > wid; --j) Cb = fmaf(A64, Cb, sE[j]);
        float ebex = __shfl_down(eb, 1, 64);
        const float cb = ((lane == 63) ? 0.0f : ebex) + pAr * Cb;
        {
            float pw = a;
            #pragma unroll
            for (int i = CHUNK-1; i >= 0; --i) { y[i] = fmaf(pw, cb, y[i]); pw *= a; }
        }

        #pragma unroll
        for (int i = 0; i < CHUNK; ++i) Mv[i] = fmaf(wk[k], y[i], Mv[i]);
    }

    // ---- epilogue: M' = exp(-alpha*(ln eps + log1p(M/eps))); out = (x*M'+delta)^r - delta^r ----
    float4* op = (float4*)(out + base);
    #pragma unroll
    for (int j = 0; j < 4; ++j) {
        float o[4];
        #pragma unroll
        for (int q = 0; q < 4; ++q) {
            const int i = 4*j + q;
            const float t  = LOG_EPS_F + log1pf(Mv[i] * 1.0e6f);
            const float Mp = expf(-alpha * t);
            const float v  = fmaf(xv[i], Mp, delta);
            o[q] = expf(rr * logf(v)) - dr;
        }
        op[j] = make_float4(o[0], o[1], o[2], o[3]);
    }
}

extern "C" void kernel_launch(void* const* d_in, const int* in_sizes, int n_in,
                              void* d_out, int out_size, void* d_ws, size_t ws_size,
                              hipStream_t stream) {
    const float* x  = (const float*)d_in[0];
    const float* la = (const float*)d_in[1];
    const float* ld = (const float*)d_in[2];
    const float* lr = (const float*)d_in[3];
    const float* zk = (const float*)d_in[4];
    float* o = (float*)d_out;
    (void)in_sizes; (void)n_in; (void)out_size; (void)d_ws; (void)ws_size;
    hipLaunchKernelGGL(pcen_kernel, dim3(NROWS), dim3(256), 0, stream,
                       x, la, ld, lr, zk, o);
}

// Round 3
// 39.274 us; speedup vs baseline: 2.2014x; 2.2014x over previous
//
#include <hip/hip_runtime.h>
#include <math.h>

#define T_DIM 4096
#define F_DIM 256
#define NROWS 4096          // B*C*F = 16*1*256
#define CHUNK 16            // elements per thread; 256 threads * 16 = 4096 = T
#define LOG2E 1.4426950408889634f

typedef float v2f __attribute__((ext_vector_type(2)));

__device__ __forceinline__ float fexp2(float v) { return __builtin_amdgcn_exp2f(v); }
__device__ __forceinline__ float flog2(float v) { return __builtin_amdgcn_logf(v); }
__device__ __forceinline__ float fexp(float v)  { return fexp2(v * LOG2E); }

__host__ __device__ constexpr float cpow(float b, int e) {
    float r = 1.0f;
    for (int i = 0; i < e; ++i) r *= b;
    return r;
}

template<int N> struct PT { float v[N]; };
template<int N>
__host__ __device__ constexpr PT<N> mk_pows(float a) {
    PT<N> t{}; float p = 1.0f;
    for (int i = 0; i < N; ++i) { t.v[i] = p; p *= a; }
    return t;
}

__device__ __forceinline__ v2f shfl_up2(v2f v, int d) {
    v2f r; r.x = __shfl_up(v.x, d, 64); r.y = __shfl_up(v.y, d, 64); return r;
}
__device__ __forceinline__ v2f shfl_down2(v2f v, int d) {
    v2f r; r.x = __shfl_down(v.x, d, 64); r.y = __shfl_down(v.y, d, 64); return r;
}

// filtfilt smoother for two scales simultaneously (packed f32).
// y[i] holds {scale K0, scale K1} results for this thread's CHUNK elements.
template<int K0, int K1>
__device__ __forceinline__ void smooth_pair(const float xv[CHUNK], v2f y[CHUNK],
                                            int tid, int lane, int wid, v2f* sE)
{
    constexpr float SL0 = (K0==0)?0.015f:(K0==1)?0.02f:(K0==2)?0.04f:0.08f;
    constexpr float SL1 = (K1==0)?0.015f:(K1==1)?0.02f:(K1==2)?0.04f:0.08f;
    constexpr float a0 = 1.0f - SL0, a1 = 1.0f - SL1;
    constexpr float A0 = cpow(a0, CHUNK), A1 = cpow(a1, CHUNK);   // a^16
    constexpr float A64_0 = cpow(a0, 64*CHUNK), A64_1 = cpow(a1, 64*CHUNK); // a^1024
    constexpr PT<CHUNK+1> P0 = mk_pows<CHUNK+1>(a0);   // a^i, i=0..16
    constexpr PT<CHUNK+1> P1 = mk_pows<CHUNK+1>(a1);
    constexpr PT<33> PA0 = mk_pows<33>(A0);            // A^d, d=0..32
    constexpr PT<33> PA1 = mk_pows<33>(A1);

    const v2f av = {a0, a1};
    const v2f sv = {SL0, SL1};
    const v2f A64v = {A64_0, A64_1};
    const float lgA0 = flog2(A0), lgA1 = flog2(A1);
    const v2f zero = {0.0f, 0.0f};

    // ===== forward: y[n] = a*y[n-1] + s*x[n], y[0] = x[0] =====
    {
        v2f x0 = {xv[0], xv[0]};
        y[0] = (tid == 0) ? x0 : (sv * x0);
    }
    #pragma unroll
    for (int i = 1; i < CHUNK; ++i) {
        v2f xi = {xv[i], xv[i]};
        y[i] = av * y[i-1] + sv * xi;
    }
    {
        // wave-level inclusive scan of chunk carries (uniform multiplier A)
        v2f e = y[CHUNK-1];
        #pragma unroll
        for (int st = 0; st < 6; ++st) {
            const int d = 1 << st;
            const v2f Ad = {PA0.v[d], PA1.v[d]};
            v2f t = shfl_up2(e, d);
            if (lane >= d) e = Ad * t + e;
        }
        __syncthreads();                 // protect sE reuse
        if (lane == 63) sE[wid] = e;
        __syncthreads();
        v2f C = zero;
        for (int j = 0; j < wid; ++j) C = A64v * C + sE[j];
        v2f eex = shfl_up2(e, 1);
        v2f cprev = (lane == 0) ? zero : eex;
        const float fl = (float)lane;
        v2f pAl = {fexp2(fl * lgA0), fexp2(fl * lgA1)};   // A^lane
        v2f c = cprev + pAl * C;         // carry entering this thread
        #pragma unroll
        for (int i = 0; i < CHUNK; ++i) {
            const v2f ap = {P0.v[i+1], P1.v[i+1]};
            y[i] = ap * c + y[i];
        }
    }

    // ===== backward (in place): z[n] = a*z[n+1] + s*y[n], z[T-1] = y[T-1] =====
    y[CHUNK-1] = (tid == 255) ? y[CHUNK-1] : (sv * y[CHUNK-1]);
    #pragma unroll
    for (int i = CHUNK-2; i >= 0; --i) y[i] = av * y[i+1] + sv * y[i];
    {
        v2f e = y[0];
        #pragma unroll
        for (int st = 0; st < 6; ++st) {
            const int d = 1 << st;
            const v2f Ad = {PA0.v[d], PA1.v[d]};
            v2f t = shfl_down2(e, d);
            if (lane < 64 - d) e = Ad * t + e;
        }
        __syncthreads();
        if (lane == 0) sE[wid] = e;
        __syncthreads();
        v2f C = zero;
        for (int j = 3; j > wid; --j) C = A64v * C + sE[j];
        v2f eex = shfl_down2(e, 1);
        v2f cnext = (lane == 63) ? zero : eex;
        const float frl = (float)(63 - lane);
        v2f pAr = {fexp2(frl * lgA0), fexp2(frl * lgA1)};  // A^(63-lane)
        v2f c = cnext + pAr * C;
        #pragma unroll
        for (int i = CHUNK-1; i >= 0; --i) {
            const v2f ap = {P0.v[CHUNK-i], P1.v[CHUNK-i]};
            y[i] = ap * c + y[i];
        }
    }
}

__global__ __launch_bounds__(256, 4)
void pcen_kernel(const float* __restrict__ x,
                 const float* __restrict__ log_alpha,
                 const float* __restrict__ log_delta,
                 const float* __restrict__ log_r,
                 const float* __restrict__ z_ks,
                 float* __restrict__ out)
{
    const int tid  = threadIdx.x;
    const int lane = tid & 63;
    const int wid  = tid >> 6;
    const int rid  = blockIdx.x;
    const int f    = rid & (F_DIM - 1);

    __shared__ float sred[4];
    __shared__ v2f   sE[4];
    __shared__ float sSum;

    // ---- softmax denominator over ALL K*F = 1024 z entries ----
    float zs = fexp(z_ks[tid])       + fexp(z_ks[tid + 256])
             + fexp(z_ks[tid + 512]) + fexp(z_ks[tid + 768]);
    #pragma unroll
    for (int d = 32; d >= 1; d >>= 1) zs += __shfl_down(zs, d, 64);
    if (lane == 0) sred[wid] = zs;
    __syncthreads();
    if (tid == 0) sSum = sred[0] + sred[1] + sred[2] + sred[3];
    __syncthreads();
    const float invsum = 1.0f / sSum;

    float wk[4];
    #pragma unroll
    for (int k = 0; k < 4; ++k) wk[k] = fexp(z_ks[k * F_DIM + f]) * invsum;
    const float alpha = fexp(log_alpha[f]);
    const float delta = fexp(log_delta[f]);
    const float rr    = fexp(log_r[f]);
    const float dr    = fexp2(rr * flog2(delta));   // delta^r (delta > 0)
    const float nalpha = -alpha;

    // ---- load this thread's 16 contiguous elements ----
    const size_t base = (size_t)rid * T_DIM + (size_t)tid * CHUNK;
    float xv[CHUNK];
    {
        const float4* xp = (const float4*)(x + base);
        #pragma unroll
        for (int j = 0; j < 4; ++j) {
            float4 v = xp[j];
            xv[4*j+0] = v.x; xv[4*j+1] = v.y; xv[4*j+2] = v.z; xv[4*j+3] = v.w;
        }
    }

    v2f y[CHUNK];
    v2f Mpk[CHUNK];

    smooth_pair<0,1>(xv, y, tid, lane, wid, sE);
    {
        const v2f wv = {wk[0], wk[1]};
        #pragma unroll
        for (int i = 0; i < CHUNK; ++i) Mpk[i] = wv * y[i];
    }
    smooth_pair<2,3>(xv, y, tid, lane, wid, sE);
    {
        const v2f wv = {wk[2], wk[3]};
        #pragma unroll
        for (int i = 0; i < CHUNK; ++i) Mpk[i] = wv * y[i] + Mpk[i];
    }

    // ---- epilogue: M' = (M+eps)^(-alpha); out = (x*M'+delta)^r - delta^r ----
    float4* op = (float4*)(out + base);
    #pragma unroll
    for (int j = 0; j < 4; ++j) {
        float o[4];
        #pragma unroll
        for (int q = 0; q < 4; ++q) {
            const int i = 4*j + q;
            const float M  = Mpk[i].x + Mpk[i].y;
            const float Mp = fexp2(nalpha * flog2(M + 1.0e-6f));
            const float v  = fmaf(xv[i], Mp, delta);
            o[q] = fexp2(rr * flog2(v)) - dr;
        }
        op[j] = make_float4(o[0], o[1], o[2], o[3]);
    }
}

extern "C" void kernel_launch(void* const* d_in, const int* in_sizes, int n_in,
                              void* d_out, int out_size, void* d_ws, size_t ws_size,
                              hipStream_t stream) {
    const float* x  = (const float*)d_in[0];
    const float* la = (const float*)d_in[1];
    const float* ld = (const float*)d_in[2];
    const float* lr = (const float*)d_in[3];
    const float* zk = (const float*)d_in[4];
    float* o = (float*)d_out;
    (void)in_sizes; (void)n_in; (void)out_size; (void)d_ws; (void)ws_size;
    hipLaunchKernelGGL(pcen_kernel, dim3(NROWS), dim3(256), 0, stream,
                       x, la, ld, lr, zk, o);
}

// Round 4
// 35.682 us; speedup vs baseline: 2.4230x; 1.1007x over previous
//
#include <hip/hip_runtime.h>
#include <math.h>

#define T_DIM 4096
#define F_DIM 256
#define NROWS 4096          // B*C*F = 16*1*256
#define CHUNK 16            // elements per thread; 256 threads * 16 = 4096 = T
#define LOG2E 1.4426950408889634f

typedef float v2f __attribute__((ext_vector_type(2)));

__device__ __forceinline__ float fexp2(float v) { return __builtin_amdgcn_exp2f(v); }
__device__ __forceinline__ float flog2(float v) { return __builtin_amdgcn_logf(v); }
__device__ __forceinline__ float fexp(float v)  { return fexp2(v * LOG2E); }

__host__ __device__ constexpr float cpow(float b, int e) {
    float r = 1.0f;
    for (int i = 0; i < e; ++i) r *= b;
    return r;
}

template<int N> struct PT { float v[N]; };
template<int N>
__host__ __device__ constexpr PT<N> mk_pows(float a) {
    PT<N> t{}; float p = 1.0f;
    for (int i = 0; i < N; ++i) { t.v[i] = p; p *= a; }
    return t;
}

__device__ __forceinline__ v2f shfl_up2(v2f v, int d) {
    v2f r; r.x = __shfl_up(v.x, d, 64); r.y = __shfl_up(v.y, d, 64); return r;
}
__device__ __forceinline__ v2f shfl_down2(v2f v, int d) {
    v2f r; r.x = __shfl_down(v.x, d, 64); r.y = __shfl_down(v.y, d, 64); return r;
}

// scale constants
#define S0 0.015f
#define S1 0.02f
#define S2 0.04f
#define S3 0.08f

__global__ __launch_bounds__(256, 4)
void pcen_kernel(const float* __restrict__ x,
                 const float* __restrict__ log_alpha,
                 const float* __restrict__ log_delta,
                 const float* __restrict__ log_r,
                 const float* __restrict__ z_ks,
                 float* __restrict__ out)
{
    const int tid  = threadIdx.x;
    const int lane = tid & 63;
    const int wid  = tid >> 6;
    const int rid  = blockIdx.x;
    const int f    = rid & (F_DIM - 1);

    __shared__ float sred[4];
    __shared__ v2f   sE0[4];
    __shared__ v2f   sE1[4];
    __shared__ float sSum;

    // ---- issue this thread's 16 global loads FIRST (hide HBM latency under prologue) ----
    const size_t base = (size_t)rid * T_DIM + (size_t)tid * CHUNK;
    const float4* xp = (const float4*)(x + base);
    float4 xq0 = xp[0], xq1 = xp[1], xq2 = xp[2], xq3 = xp[3];

    // ---- softmax denominator over ALL K*F = 1024 z entries ----
    float zs = fexp(z_ks[tid])       + fexp(z_ks[tid + 256])
             + fexp(z_ks[tid + 512]) + fexp(z_ks[tid + 768]);
    #pragma unroll
    for (int d = 32; d >= 1; d >>= 1) zs += __shfl_down(zs, d, 64);
    if (lane == 0) sred[wid] = zs;
    __syncthreads();
    if (tid == 0) sSum = sred[0] + sred[1] + sred[2] + sred[3];
    __syncthreads();
    const float invsum = 1.0f / sSum;

    float wk[4];
    #pragma unroll
    for (int k = 0; k < 4; ++k) wk[k] = fexp(z_ks[k * F_DIM + f]) * invsum;
    const float alpha = fexp(log_alpha[f]);
    const float delta = fexp(log_delta[f]);
    const float rr    = fexp(log_r[f]);
    const float dr    = fexp2(rr * flog2(delta));   // delta^r (delta > 0)
    const float nalpha = -alpha;

    float xv[CHUNK];
    xv[0]=xq0.x; xv[1]=xq0.y; xv[2]=xq0.z; xv[3]=xq0.w;
    xv[4]=xq1.x; xv[5]=xq1.y; xv[6]=xq1.z; xv[7]=xq1.w;
    xv[8]=xq2.x; xv[9]=xq2.y; xv[10]=xq2.z; xv[11]=xq2.w;
    xv[12]=xq3.x; xv[13]=xq3.y; xv[14]=xq3.z; xv[15]=xq3.w;

    // ---- compile-time coefficient tables for all 4 scales (pairs {0,1} and {2,3}) ----
    constexpr float a0 = 1.0f - S0, a1 = 1.0f - S1, a2 = 1.0f - S2, a3 = 1.0f - S3;
    constexpr float A0 = cpow(a0, CHUNK), A1 = cpow(a1, CHUNK);
    constexpr float A2 = cpow(a2, CHUNK), A3 = cpow(a3, CHUNK);
    constexpr float A64_0 = cpow(a0, 64*CHUNK), A64_1 = cpow(a1, 64*CHUNK);
    constexpr float A64_2 = cpow(a2, 64*CHUNK), A64_3 = cpow(a3, 64*CHUNK);
    constexpr PT<CHUNK+1> P0 = mk_pows<CHUNK+1>(a0);
    constexpr PT<CHUNK+1> P1 = mk_pows<CHUNK+1>(a1);
    constexpr PT<CHUNK+1> P2 = mk_pows<CHUNK+1>(a2);
    constexpr PT<CHUNK+1> P3 = mk_pows<CHUNK+1>(a3);
    constexpr PT<33> PA0 = mk_pows<33>(A0);
    constexpr PT<33> PA1 = mk_pows<33>(A1);
    constexpr PT<33> PA2 = mk_pows<33>(A2);
    constexpr PT<33> PA3 = mk_pows<33>(A3);

    const v2f av01 = {a0, a1}, av23 = {a2, a3};
    const v2f sv01 = {S0, S1}, sv23 = {S2, S3};
    const v2f A64v01 = {A64_0, A64_1}, A64v23 = {A64_2, A64_3};
    const float lgA0 = flog2(A0), lgA1 = flog2(A1), lgA2 = flog2(A2), lgA3 = flog2(A3);
    const v2f zero = {0.0f, 0.0f};

    v2f y0[CHUNK], y1[CHUNK];   // pair {s0,s1} and pair {s2,s3}

    // ===== forward: y[n] = a*y[n-1] + s*x[n], y[0] = x[0] =====
    {
        v2f x0v = {xv[0], xv[0]};
        y0[0] = (tid == 0) ? x0v : (sv01 * x0v);
        y1[0] = (tid == 0) ? x0v : (sv23 * x0v);
    }
    #pragma unroll
    for (int i = 1; i < CHUNK; ++i) {
        v2f xi = {xv[i], xv[i]};
        y0[i] = av01 * y0[i-1] + sv01 * xi;
        y1[i] = av23 * y1[i-1] + sv23 * xi;
    }
    {
        // wave-level inclusive scan of chunk carries (both pairs interleaved)
        v2f e0 = y0[CHUNK-1], e1 = y1[CHUNK-1];
        #pragma unroll
        for (int st = 0; st < 6; ++st) {
            const int d = 1 << st;
            const v2f Ad01 = {PA0.v[d], PA1.v[d]};
            const v2f Ad23 = {PA2.v[d], PA3.v[d]};
            v2f t0 = shfl_up2(e0, d);
            v2f t1 = shfl_up2(e1, d);
            if (lane >= d) { e0 = Ad01 * t0 + e0; e1 = Ad23 * t1 + e1; }
        }
        if (lane == 63) { sE0[wid] = e0; sE1[wid] = e1; }
        __syncthreads();
        v2f C0 = zero, C1 = zero;
        for (int j = 0; j < wid; ++j) {
            C0 = A64v01 * C0 + sE0[j];
            C1 = A64v23 * C1 + sE1[j];
        }
        v2f ex0 = shfl_up2(e0, 1), ex1 = shfl_up2(e1, 1);
        v2f cp0 = (lane == 0) ? zero : ex0;
        v2f cp1 = (lane == 0) ? zero : ex1;
        const float fl = (float)lane;
        v2f pAl01 = {fexp2(fl * lgA0), fexp2(fl * lgA1)};
        v2f pAl23 = {fexp2(fl * lgA2), fexp2(fl * lgA3)};
        v2f c0 = cp0 + pAl01 * C0;
        v2f c1 = cp1 + pAl23 * C1;
        #pragma unroll
        for (int i = 0; i < CHUNK; ++i) {
            const v2f ap01 = {P0.v[i+1], P1.v[i+1]};
            const v2f ap23 = {P2.v[i+1], P3.v[i+1]};
            y0[i] = ap01 * c0 + y0[i];
            y1[i] = ap23 * c1 + y1[i];
        }
    }

    // ===== backward (in place): z[n] = a*z[n+1] + s*y[n], z[T-1] = y[T-1] =====
    y0[CHUNK-1] = (tid == 255) ? y0[CHUNK-1] : (sv01 * y0[CHUNK-1]);
    y1[CHUNK-1] = (tid == 255) ? y1[CHUNK-1] : (sv23 * y1[CHUNK-1]);
    #pragma unroll
    for (int i = CHUNK-2; i >= 0; --i) {
        y0[i] = av01 * y0[i+1] + sv01 * y0[i];
        y1[i] = av23 * y1[i+1] + sv23 * y1[i];
    }
    {
        v2f e0 = y0[0], e1 = y1[0];
        #pragma unroll
        for (int st = 0; st < 6; ++st) {
            const int d = 1 << st;
            const v2f Ad01 = {PA0.v[d], PA1.v[d]};
            const v2f Ad23 = {PA2.v[d], PA3.v[d]};
            v2f t0 = shfl_down2(e0, d);
            v2f t1 = shfl_down2(e1, d);
            if (lane < 64 - d) { e0 = Ad01 * t0 + e0; e1 = Ad23 * t1 + e1; }
        }
        __syncthreads();                 // sE reuse guard
        if (lane == 0) { sE0[wid] = e0; sE1[wid] = e1; }
        __syncthreads();
        v2f C0 = zero, C1 = zero;
        for (int j = 3; j > wid; --j) {
            C0 = A64v01 * C0 + sE0[j];
            C1 = A64v23 * C1 + sE1[j];
        }
        v2f ex0 = shfl_down2(e0, 1), ex1 = shfl_down2(e1, 1);
        v2f cn0 = (lane == 63) ? zero : ex0;
        v2f cn1 = (lane == 63) ? zero : ex1;
        const float frl = (float)(63 - lane);
        v2f pAr01 = {fexp2(frl * lgA0), fexp2(frl * lgA1)};
        v2f pAr23 = {fexp2(frl * lgA2), fexp2(frl * lgA3)};
        v2f c0 = cn0 + pAr01 * C0;
        v2f c1 = cn1 + pAr23 * C1;
        #pragma unroll
        for (int i = CHUNK-1; i >= 0; --i) {
            const v2f ap01 = {P0.v[CHUNK-i], P1.v[CHUNK-i]};
            const v2f ap23 = {P2.v[CHUNK-i], P3.v[CHUNK-i]};
            y0[i] = ap01 * c0 + y0[i];
            y1[i] = ap23 * c1 + y1[i];
        }
    }

    // ---- epilogue: M = Σ w_k y_k; M' = (M+eps)^(-alpha); out = (x*M'+delta)^r - delta^r ----
    float4* op = (float4*)(out + base);
    const v2f wv01 = {wk[0], wk[1]}, wv23 = {wk[2], wk[3]};
    #pragma unroll
    for (int j = 0; j < 4; ++j) {
        float o[4];
        #pragma unroll
        for (int q = 0; q < 4; ++q) {
            const int i = 4*j + q;
            v2f mp = wv01 * y0[i] + wv23 * y1[i];
            const float M  = mp.x + mp.y;
            const float Mp = fexp2(nalpha * flog2(M + 1.0e-6f));
            const float v  = fmaf(xv[i], Mp, delta);
            o[q] = fexp2(rr * flog2(v)) - dr;
        }
        op[j] = make_float4(o[0], o[1], o[2], o[3]);
    }
}

extern "C" void kernel_launch(void* const* d_in, const int* in_sizes, int n_in,
                              void* d_out, int out_size, void* d_ws, size_t ws_size,
                              hipStream_t stream) {
    const float* x  = (const float*)d_in[0];
    const float* la = (const float*)d_in[1];
    const float* ld = (const float*)d_in[2];
    const float* lr = (const float*)d_in[3];
    const float* zk = (const float*)d_in[4];
    float* o = (float*)d_out;
    (void)in_sizes; (void)n_in; (void)out_size; (void)d_ws; (void)ws_size;
    hipLaunchKernelGGL(pcen_kernel, dim3(NROWS), dim3(256), 0, stream,
                       x, la, ld, lr, zk, o);
}